// Round 17
// baseline (620.185 us; speedup 1.0000x reference)
//
#include <hip/hip_runtime.h>
#include <math.h>

typedef unsigned short u16;
typedef __bf16 bf16x8 __attribute__((ext_vector_type(8)));
typedef float f32x4 __attribute__((ext_vector_type(4)));
typedef u16 u16x8 __attribute__((ext_vector_type(8)));

#define DEVI static __device__ __forceinline__

#define NB 16
#define SEQ 2048
#define DM 512
#define DH 64
#define NF 266
#define NFP 288
#define FFD 2048
#define ROWS (NB*SEQ)
#define SQRT_DM 22.62741699796952f
#define DATA_NORM 0.3535533905932738f
#define RATIO 0.0613139073f
#define KEPS 1e-4f

DEVI u16 f2b(float f){
  union{float f; unsigned u;} c; c.f=f;
  unsigned r = c.u + 0x7FFFu + ((c.u>>16)&1u);
  return (u16)(r>>16);
}
DEVI float b2f(u16 v){
  union{unsigned u; float f;} c; c.u = ((unsigned)v)<<16; return c.f;
}
DEVI unsigned cvtpk(float a, float b){
  unsigned r;
  asm("v_cvt_pk_bf16_f32 %0, %1, %2" : "=v"(r) : "v"(a), "v"(b));
  return r;
}

DEVI f32x4 MFMA(bf16x8 a, bf16x8 b, f32x4 c){
  return __builtin_amdgcn_mfma_f32_16x16x32_bf16(a,b,c,0,0,0);
}

DEVI void async16(void* lds, const void* g){
  __builtin_amdgcn_global_load_lds(
      (const __attribute__((address_space(1))) unsigned*)g,
      (__attribute__((address_space(3))) unsigned*)lds, 16, 0, 0);
}

DEVI void atomicMaxF(float* a, float v){
  if (v >= 0.f) atomicMax((int*)a, __float_as_int(v));
  else          atomicMin((unsigned*)a, (unsigned)__float_as_int(v));
}

DEVI bf16x8 ldb8(const u16* p){ return *(const bf16x8*)p; }

// erf via Abramowitz-Stegun 7.1.26 (|err| < 1.5e-7)
DEVI float erf_fast(float u){
  float au = fabsf(u);
  float tt = __builtin_amdgcn_rcpf(1.f + 0.3275911f*au);
  float poly = tt*(0.254829592f + tt*(-0.284496736f + tt*(1.421413741f + tt*(-1.453152027f + tt*1.061405429f))));
  float er = 1.f - poly*__expf(-u*u);
  return copysignf(er, u);
}

// ============ 256xBNT tile GEMM, BK=32, 8 waves, 3-buffer + 2-phase interleave ============
// Counted vmcnt (never 0 mid-loop): outstanding after each K-tile = the t+2 stage batch.
// Phases: {stage-issue || ds_read half A-frags; barrier; lgkmcnt(0); 16-MFMA cluster; barrier}.
// EPI: 1 = bias -> bf16 out; 2 = bias+gelu -> bf16 out; 3 = bias + resid(f32,in-place) -> f32
template<int EPI, int BNT>
__launch_bounds__(512,2)
__global__ void gemm8(const u16* __restrict__ A, int lda,
                      const u16* __restrict__ Bt, int ldb,
                      const float* __restrict__ bias,
                      float* __restrict__ resid,
                      u16* __restrict__ Cb,
                      int N, int K)
{
  constexpr int NREG = BNT/64;             // 4 or 2 accumulator cols per wave
  constexpr int LDSB = 8192 + BNT*32;      // u16 per K-tile buffer (A 16KB + B)
  __shared__ u16 sm[3*LDSB];
  const int tid = threadIdx.x;
  const int ntn = N / BNT;
  int bid = blockIdx.x;
  const int nwg = gridDim.x;
  if ((nwg & 7) == 0){ int qq = nwg >> 3; bid = (bid & 7)*qq + (bid >> 3); }
  const int bm = bid / ntn, bn = bid % ntn;
  const int wid = tid>>6, l = tid&63, lr = l&15, lg = l>>4;
  const int wm = wid>>2, wn = wid&3;

  // staging source (pre-swizzled chunk)
  const int rA = tid>>2;
  const int cA = (tid&3) ^ ((rA>>1)&3);
  const u16* gA = A  + (size_t)(bm*256 + rA)*lda + cA*8;
  const u16* gB = Bt + (size_t)(bn*BNT + rA)*ldb + cA*8;
  const size_t stepA = (size_t)128*lda, stepB = (size_t)128*ldb;

  // frag read offsets (swizzle constant per thread)
  const int cc = ((lg ^ ((lr>>1)&3))<<3);
  const int aoff = (wm*128 + lr)*32 + cc;
  const int boff = 8192 + (wn*(BNT/4) + lr)*32 + cc;

  const int nt = K >> 5;
  f32x4 acc[8][NREG];
  #pragma unroll
  for (int m=0;m<8;m++)
    #pragma unroll
    for (int n=0;n<NREG;n++) acc[m][n]=(f32x4){0.f,0.f,0.f,0.f};

  // stage helpers: half 0 = A (2 loads), half 1 = B (2 or 1 loads)
  auto stageA = [&](int bufi, int t){
    u16* sb = &sm[bufi*LDSB];
    const u16* a0 = gA + t*32;
    async16(&sb[tid*8],        a0);
    async16(&sb[4096 + tid*8], a0 + stepA);
  };
  auto stageB = [&](int bufi, int t){
    u16* sb = &sm[bufi*LDSB];
    const u16* b0 = gB + t*32;
    async16(&sb[8192 + tid*8], b0);
    if (BNT == 256) async16(&sb[12288 + tid*8], b0 + stepB);
  };

  // prologue: stage tiles 0 and 1
  stageA(0,0); stageB(0,0);
  stageA(1,1); stageB(1,1);
  if constexpr (BNT == 256) asm volatile("s_waitcnt vmcnt(4)" ::: "memory");
  else                      asm volatile("s_waitcnt vmcnt(3)" ::: "memory");
  __builtin_amdgcn_s_barrier();
  __builtin_amdgcn_sched_barrier(0);

  int bufc = 0;
  for (int t=0; t<nt; ++t){
    const u16* sb = &sm[bufc*LDSB];
    int bufn = bufc+2; if (bufn>=3) bufn-=3;
    const bool pre = (t+2 < nt);
    bf16x8 bfr[NREG];

    // ---- phase 0: stage A(t+2) || read bfr + af[0..3]; 16(8)-MFMA m=0..3 ----
    if (pre) stageA(bufn, t+2);
    bf16x8 af0 = ldb8(&sb[aoff + 0*512]);
    bf16x8 af1 = ldb8(&sb[aoff + 1*512]);
    bf16x8 af2 = ldb8(&sb[aoff + 2*512]);
    bf16x8 af3 = ldb8(&sb[aoff + 3*512]);
    #pragma unroll
    for (int n=0;n<NREG;n++) bfr[n] = ldb8(&sb[boff + n*512]);
    __builtin_amdgcn_s_barrier();
    asm volatile("s_waitcnt lgkmcnt(0)" ::: "memory");
    __builtin_amdgcn_sched_barrier(0);
    __builtin_amdgcn_s_setprio(1);
    #pragma unroll
    for (int n=0;n<NREG;n++){
      acc[0][n] = MFMA(af0, bfr[n], acc[0][n]);
      acc[1][n] = MFMA(af1, bfr[n], acc[1][n]);
      acc[2][n] = MFMA(af2, bfr[n], acc[2][n]);
      acc[3][n] = MFMA(af3, bfr[n], acc[3][n]);
    }
    __builtin_amdgcn_s_setprio(0);
    __builtin_amdgcn_s_barrier();

    // ---- phase 1: stage B(t+2) || read af[4..7]; 16(8)-MFMA m=4..7 ----
    if (pre) stageB(bufn, t+2);
    bf16x8 af4 = ldb8(&sb[aoff + 4*512]);
    bf16x8 af5 = ldb8(&sb[aoff + 5*512]);
    bf16x8 af6 = ldb8(&sb[aoff + 6*512]);
    bf16x8 af7 = ldb8(&sb[aoff + 7*512]);
    __builtin_amdgcn_s_barrier();
    asm volatile("s_waitcnt lgkmcnt(0)" ::: "memory");
    __builtin_amdgcn_sched_barrier(0);
    __builtin_amdgcn_s_setprio(1);
    #pragma unroll
    for (int n=0;n<NREG;n++){
      acc[4][n] = MFMA(af4, bfr[n], acc[4][n]);
      acc[5][n] = MFMA(af5, bfr[n], acc[5][n]);
      acc[6][n] = MFMA(af6, bfr[n], acc[6][n]);
      acc[7][n] = MFMA(af7, bfr[n], acc[7][n]);
    }
    __builtin_amdgcn_s_setprio(0);

    // ---- K-tile end: counted vmcnt proves t+1's loads retired ----
    if (t+1 < nt){
      if (pre){
        if constexpr (BNT == 256) asm volatile("s_waitcnt vmcnt(4)" ::: "memory");
        else                      asm volatile("s_waitcnt vmcnt(3)" ::: "memory");
      } else {
        asm volatile("s_waitcnt vmcnt(0)" ::: "memory");
      }
      __builtin_amdgcn_s_barrier();
      __builtin_amdgcn_sched_barrier(0);
    }
    bufc = bufc+1; if (bufc>=3) bufc-=3;
  }

  // ---- epilogue ----
  if (EPI == 3){
    const int r0 = bm*256 + wm*128 + lg*4;
    const int c0 = bn*BNT + wn*(BNT/4) + lr;
    #pragma unroll
    for (int m=0;m<8;m++){
      #pragma unroll
      for (int n=0;n<NREG;n++){
        #pragma unroll
        for (int q=0;q<4;q++){
          int r = r0 + m*16 + q;
          int c = c0 + n*16;
          float v = acc[m][n][q] + bias[c];
          size_t idx = (size_t)r*N + c;
          resid[idx] = resid[idx] + v;
        }
      }
    }
  } else {
    // bf16 out: per-wave LDS transpose (staging LDS is dead) -> vectorized 16B stores
    __syncthreads();
    constexpr int OBW = (BNT==256) ? 72 : 40;      // padded row stride (u16)
    constexpr int OWS = (BNT==256) ? 2336 : 1280;  // per-wave region (u16)
    const int c0w = bn*BNT + wn*(BNT/4);
    const int r0m = bm*256 + wm*128;
    #pragma unroll
    for (int m=0;m<8;m++){
      u16* obw = &sm[wid*OWS + (m&1)*(OWS/2)];
      #pragma unroll
      for (int n=0;n<NREG;n++){
        #pragma unroll
        for (int q=0;q<4;q++){
          float v = acc[m][n][q] + bias[c0w + n*16 + lr];
          if (EPI==2) v = 0.5f*v*(1.f + erf_fast(v*0.70710678f));
          obw[(lg*4+q)*OBW + n*16 + lr] = f2b(v);
        }
      }
      asm volatile("s_waitcnt lgkmcnt(0)" ::: "memory");
      if (BNT == 256){
        int rowR = l>>3, ck = l&7;
        #pragma unroll
        for (int rr=0; rr<2; ++rr){
          int r2 = rowR + rr*8;
          uint4 v = *(const uint4*)&obw[r2*OBW + ck*8];
          *(uint4*)(Cb + (size_t)(r0m + m*16 + r2)*N + c0w + ck*8) = v;
        }
      } else {
        int rowR = l>>2, ck = l&3;
        uint4 v = *(const uint4*)&obw[rowR*OBW + ck*8];
        *(uint4*)(Cb + (size_t)(r0m + m*16 + rowR)*N + c0w + ck*8) = v;
      }
    }
  }
}

// ---------------- fused weight prep: LDS-tiled transposes + misc ----------------
__launch_bounds__(256)
__global__ void k_prep(const float* __restrict__ wq, const float* __restrict__ wk,
                       const float* __restrict__ wv, const float* __restrict__ wo,
                       const float* __restrict__ ffw1, const float* __restrict__ ffw2,
                       const float* __restrict__ proj, const float* __restrict__ bk,
                       const float* __restrict__ bv,
                       u16* __restrict__ wqT, u16* __restrict__ wkvT, u16* __restrict__ woT,
                       u16* __restrict__ f1T, u16* __restrict__ f2T, u16* __restrict__ pjn,
                       float* __restrict__ kvb, float* __restrict__ pbuf)
{
  int bid = blockIdx.x, t = threadIdx.x;
  if (bid < 3072){
    const float* src; u16* dst; int R, C, tile;
    if      (bid < 256){ src=wq;  dst=wqT;          R=512; C=512;  tile=bid; }
    else if (bid < 512){ src=wk;  dst=wkvT;         R=512; C=512;  tile=bid-256; }
    else if (bid < 768){ src=wv;  dst=wkvT+262144;  R=512; C=512;  tile=bid-512; }
    else if (bid <1024){ src=wo;  dst=woT;          R=512; C=512;  tile=bid-768; }
    else if (bid <2048){ src=ffw1;dst=f1T;          R=512; C=2048; tile=bid-1024; }
    else               { src=ffw2;dst=f2T;          R=2048;C=512;  tile=bid-2048; }
    int ntc = C>>5;
    int tr = tile/ntc, tc = tile%ntc;
    __shared__ float tl[32][33];
    int r = t>>5, c = t&31;
    #pragma unroll
    for (int it=0; it<4; ++it)
      tl[r+it*8][c] = src[(size_t)(tr*32 + r + it*8)*C + tc*32 + c];
    __syncthreads();
    #pragma unroll
    for (int it=0; it<4; ++it)
      dst[(size_t)(tc*32 + r + it*8)*R + tr*32 + c] = f2b(tl[c][r+it*8]);
    return;
  }
  int i = (bid-3072)*256 + t;
  if (i < NFP*DH){ int f=i>>6, d=i&63; pjn[i] = f2b(f<NF ? proj[(size_t)f*64+d]*DATA_NORM : 0.f); return; }
  i -= NFP*DH;
  if (i < 1024){ kvb[i] = (i<512)? bk[i] : bv[i-512]; return; }
  i -= 1024;
  if (i < NB*DM){ pbuf[i] = -INFINITY; return; }
}

__global__ void k_signal(float* out, float v){
  if (threadIdx.x==0 && blockIdx.x==0) out[0] = v;
}

// ---------------- encoder + LN1 (one wave per row) ----------------
__launch_bounds__(256)
__global__ void k_encode_ln(const float* __restrict__ x, const float* __restrict__ ew,
                            const float* __restrict__ eb, const float* __restrict__ lgw,
                            const float* __restrict__ lbw, float* __restrict__ h,
                            u16* __restrict__ y)
{
  int w = threadIdx.x>>6, l = threadIdx.x&63;
  int row = blockIdx.x*4 + w;
  const float* xr = x + (size_t)row*24;
  float xv[24];
  #pragma unroll
  for (int k=0;k<24;k++) xv[k] = xr[k];
  int c0 = l*8;
  float a[8] = {0,0,0,0,0,0,0,0};
  #pragma unroll
  for (int k=0;k<24;k++){
    const float* wp = ew + (size_t)k*DM + c0;
    #pragma unroll
    for (int c=0;c<8;c++) a[c] += xv[k]*wp[c];
  }
  float s=0.f, s2=0.f;
  #pragma unroll
  for (int c=0;c<8;c++){
    a[c] = (a[c] + eb[c0+c]) * SQRT_DM;
    s += a[c]; s2 += a[c]*a[c];
  }
  #pragma unroll
  for (int m=1;m<64;m<<=1){ s += __shfl_xor(s,m); s2 += __shfl_xor(s2,m); }
  float mu = s*(1.f/DM);
  float rs = rsqrtf(s2*(1.f/DM) - mu*mu + 1e-5f);
  float* hr = h + (size_t)row*DM + c0;
  u16 yv[8];
  #pragma unroll
  for (int c=0;c<8;c++){
    hr[c] = a[c];
    yv[c] = f2b((a[c]-mu)*rs*lgw[c0+c] + lbw[c0+c]);
  }
  *(uint4*)(y + (size_t)row*DM + c0) = *(const uint4*)yv;
}

// ---------------- LN2 ----------------
__launch_bounds__(256)
__global__ void k_ln(const float* __restrict__ h, const float* __restrict__ lgw,
                     const float* __restrict__ lbw, u16* __restrict__ y)
{
  int w = threadIdx.x>>6, l = threadIdx.x&63;
  int row = blockIdx.x*4 + w;
  int c0 = l*8;
  const float* hr = h + (size_t)row*DM + c0;
  float a[8];
  *(float4*)&a[0] = *(const float4*)hr;
  *(float4*)&a[4] = *(const float4*)(hr+4);
  float s=0.f, s2=0.f;
  #pragma unroll
  for (int c=0;c<8;c++){ s += a[c]; s2 += a[c]*a[c]; }
  #pragma unroll
  for (int m=1;m<64;m<<=1){ s += __shfl_xor(s,m); s2 += __shfl_xor(s2,m); }
  float mu = s*(1.f/DM);
  float rs = rsqrtf(s2*(1.f/DM) - mu*mu + 1e-5f);
  u16 yv[8];
  #pragma unroll
  for (int c=0;c<8;c++) yv[c] = f2b((a[c]-mu)*rs*lgw[c0+c] + lbw[c0+c]);
  *(uint4*)(y + (size_t)row*DM + c0) = *(const uint4*)yv;
}

// ---------------- FAVOR+: global max over dd_k ----------------
__launch_bounds__(256,1)
__global__ void k_kmax(const u16* __restrict__ kv, const u16* __restrict__ pjn,
                       float* __restrict__ mkpart)
{
  __shared__ float red[4];
  int t = threadIdx.x, w = t>>6, l = t&63, lr = l&15, lg = l>>4;
  int bh = blockIdx.x>>3, tile = blockIdx.x&7;
  int b = bh>>3, hd = bh&7;
  int row0 = tile*256 + w*64;
  bf16x8 pf0[17], pf1[17];
  #pragma unroll
  for (int f=0; f<17; ++f){
    const u16* pb = pjn + (f*16 + lr)*64 + lg*8;
    pf0[f] = ldb8(pb); pf1[f] = ldb8(pb+32);
  }
  bf16x8 a0[4], a1[4];
  #pragma unroll
  for (int it=0; it<4; ++it){
    const u16* kb = kv + ((size_t)(b*SEQ + row0 + it*16 + lr)*1024 + hd*64 + lg*8);
    a0[it] = ldb8(kb); a1[it] = ldb8(kb+32);
  }
  float vmax = -3e38f;
  #pragma unroll
  for (int it=0; it<4; ++it){
    #pragma unroll
    for (int f=0; f<17; ++f){
      f32x4 z = (f32x4){0.f,0.f,0.f,0.f};
      z = MFMA(a0[it], pf0[f], z);
      z = MFMA(a1[it], pf1[f], z);
      if (f*16 + lr < NF){
        #pragma unroll
        for (int j=0;j<4;j++) vmax = fmaxf(vmax, z[j]);
      }
    }
  }
  #pragma unroll
  for (int m=1;m<64;m<<=1) vmax = fmaxf(vmax, __shfl_xor(vmax,m));
  if (l==0) red[w] = vmax;
  __syncthreads();
  if (t==0) mkpart[blockIdx.x] = fmaxf(fmaxf(red[0],red[1]), fmaxf(red[2],red[3]));
}

__global__ void k_kmax_red(const float* __restrict__ mkpart, float* __restrict__ mk){
  __shared__ float red[4];
  int t = threadIdx.x, w = t>>6, l = t&63;
  float v = fmaxf(fmaxf(mkpart[t], mkpart[t+256]), fmaxf(mkpart[t+512], mkpart[t+768]));
  #pragma unroll
  for (int m=1;m<64;m<<=1) v = fmaxf(v, __shfl_xor(v,m));
  if (l==0) red[w] = v;
  __syncthreads();
  if (t==0) mk[0] = fmaxf(fmaxf(red[0],red[1]), fmaxf(red[2],red[3]));
}

// ---------------- FAVOR+: kp -> ctx^T partials (bf16) + ksum partials ----------------
__launch_bounds__(256,2)
__global__ void k_kpctx(const u16* __restrict__ kv, const u16* __restrict__ pjn,
                        const float* __restrict__ mkp,
                        u16* __restrict__ ctxp, float* __restrict__ ksump)
{
  __shared__ u16 pjs[272*64];    // [272 f][64 d], 16B chunks XOR-swizzled by (row&7)
  __shared__ u16 vT[DH*32];      // [64 d][32 n], 16B chunks XOR-swizzled by (row>>1)&3
  __shared__ u16 kpT[NFP*32];    // [288 f][32 n], same swizzle
  __shared__ float dbuf[4][16];
  int t = threadIdx.x, w = t>>6, l = t&63, lr = l&15, lg = l>>4;
  int bh = blockIdx.x>>2, seg = blockIdx.x&3;
  int b = bh>>3, hd = bh&7;
  int mw = w>>1, fh = (w&1)*9;
  float mk = *mkp;

  // stage proj (first 17 f-tiles; tile 17 is all zeros -> handled in code)
  for (int i=t; i<2176; i+=256){
    int row = i>>3, cin = i&7;
    *(uint4*)&pjs[row*64 + ((cin ^ (row&7))<<3)] = ((const uint4*)pjn)[i];
  }

  f32x4 ctxa[18];
  #pragma unroll
  for (int f=0;f<18;f++) ctxa[f]=(f32x4){0.f,0.f,0.f,0.f};
  float ksa[9];
  #pragma unroll
  for (int i=0;i<9;i++) ksa[i]=0.f;

  for (int ch=0; ch<16; ++ch){
    int n0 = seg*512 + ch*32;
    __syncthreads();
    {  // stage v^T (swizzled chunks)
      int nl = t>>3, d0 = (t&7)*8;
      const u16* vsrc = kv + ((size_t)(b*SEQ + n0 + nl)*1024 + 512 + hd*64 + d0);
      uint4 vv = *(const uint4*)vsrc;
      const u16* vp = (const u16*)&vv;
      #pragma unroll
      for (int i=0;i<8;i++){
        int row = d0+i;
        vT[row*32 + (((nl>>3) ^ ((row>>1)&3))<<3) + (nl&7)] = vp[i];
      }
    }
    const u16* kb = kv + ((size_t)(b*SEQ + n0 + mw*16 + lr)*1024 + hd*64 + lg*8);
    bf16x8 a0 = ldb8(kb), a1 = ldb8(kb+32);
    float sq = 0.f;
    #pragma unroll
    for (int i=0;i<8;i++){ float u0=(float)a0[i], u1=(float)a1[i]; sq += u0*u0 + u1*u1; }
    sq += __shfl_xor(sq,16); sq += __shfl_xor(sq,32);
    if (l<16) dbuf[w][l] = sq*0.0625f;
    #pragma unroll
    for (int ff=0; ff<9; ++ff){
      int f = fh + ff;
      f32x4 z = (f32x4){0.f,0.f,0.f,0.f};
      if (f < 17){
        int row = f*16 + lr;
        const u16* pb0 = pjs + row*64 + ((lg ^ (lr&7))<<3);
        const u16* pb1 = pjs + row*64 + (((lg+4) ^ (lr&7))<<3);
        z = MFMA(a0, ldb8(pb0), z);
        z = MFMA(a1, ldb8(pb1), z);
      }
      float kp0 = RATIO*(__expf(z[0] - dbuf[w][lg*4+0] - mk) + KEPS);
      float kp1 = RATIO*(__expf(z[1] - dbuf[w][lg*4+1] - mk) + KEPS);
      float kp2 = RATIO*(__expf(z[2] - dbuf[w][lg*4+2] - mk) + KEPS);
      float kp3 = RATIO*(__expf(z[3] - dbuf[w][lg*4+3] - mk) + KEPS);
      ksa[ff] += kp0 + kp1 + kp2 + kp3;
      ushort4 kw;
      kw.x = f2b(kp0); kw.y = f2b(kp1); kw.z = f2b(kp2); kw.w = f2b(kp3);
      int row = f*16 + lr;
      int wch = (mw*2 + (lg>>1)) ^ ((row>>1)&3);
      *(ushort4*)&kpT[row*32 + (wch<<3) + ((lg&1)<<2)] = kw;
    }
    __syncthreads();
    int rr = w*16 + lr;
    bf16x8 av = ldb8(&vT[rr*32 + ((lg ^ ((rr>>1)&3))<<3)]);
    #pragma unroll
    for (int f=0;f<18;f++){
      int row = f*16 + lr;
      ctxa[f] = MFMA(av, ldb8(&kpT[row*32 + ((lg ^ ((row>>1)&3))<<3)]), ctxa[f]);
    }
  }

  // ---- transposed, vectorized ctx^T partial store ----
  __syncthreads();  // main loop done; pjs/kpT reusable as f32 [16][288] transpose buffers
  {
    float* tb = (w&1) ? (float*)pjs : (float*)kpT;
    u16* dstq = ctxp + (((size_t)seg*128 + bh)*DH + w*16)*NFP;
    #pragma unroll
    for (int r=0; r<2; ++r){
      if ((w>>1) == r){
        #pragma unroll
        for (int f=0;f<18;f++)
          #pragma unroll
          for (int j=0;j<4;j++)
            tb[(lg*4+j)*NFP + f*16 + lr] = ctxa[f][j];
        asm volatile("s_waitcnt lgkmcnt(0)" ::: "memory");
        #pragma unroll
        for (int k=0;k<9;k++){
          int c = k*64 + l;
          f32x4 v0 = *(const f32x4*)(tb + c*8);
          f32x4 v1 = *(const f32x4*)(tb + c*8 + 4);
          u16x8 o;
          o[0]=f2b(v0[0]); o[1]=f2b(v0[1]); o[2]=f2b(v0[2]); o[3]=f2b(v0[3]);
          o[4]=f2b(v1[0]); o[5]=f2b(v1[1]); o[6]=f2b(v1[2]); o[7]=f2b(v1[3]);
          *(u16x8*)(dstq + c*8) = o;
        }
      }
      __syncthreads();
    }
  }
  // ksum partial store: [seg][bh][288]
  #pragma unroll
  for (int ff=0;ff<9;ff++){
    float v = ksa[ff];
    v += __shfl_xor(v,16); v += __shfl_xor(v,32);
    if (l<16) ksump[((size_t)seg*128 + bh)*NFP + (fh+ff)*16 + l] = v;
  }
}

// ---------------- reduce 4 ctx partials (bf16) + 4 ksum partials ----------------
__global__ void k_reduce(const u16* __restrict__ ctxp, const float* __restrict__ ksump,
                         u16* __restrict__ ctxb, float* __restrict__ ksum)
{
  const size_t CT = (size_t)128*DH*NFP;
  const size_t KT = (size_t)128*NFP;
  size_t i = (size_t)blockIdx.x*256 + threadIdx.x;
  if (i < CT){
    float s = b2f(ctxp[i]) + b2f(ctxp[i+CT]) + b2f(ctxp[i+2*CT]) + b2f(ctxp[i+3*CT]);
    ctxb[i] = f2b(s);
  } else if (i < CT + KT){
    size_t j = i - CT;
    ksum[j] = ksump[j] + ksump[j+KT] + ksump[j+2*KT] + ksump[j+3*KT];
  }
}

// ---------------- FAVOR+: qp + attention out ((256,3), 84 VGPR; pjn staged in LDS) ----------------
__launch_bounds__(256,3)
__global__ void k_qp_attn(const u16* __restrict__ q, const u16* __restrict__ pjn,
                          const u16* __restrict__ ctxb, const float* __restrict__ ksum,
                          u16* __restrict__ attn)
{
  __shared__ u16 pjs[272*64];    // 34.8 KB, same (row&7) XOR-swizzle as k_kpctx
  __shared__ u16 ob[4][16*72];
  int t = threadIdx.x, w = t>>6, l = t&63, lr = l&15, lg = l>>4;
  int bh = blockIdx.x>>5, tile = blockIdx.x&31;
  int b = bh>>3, hd = bh&7;
  int n0 = tile*64;

  // stage proj into LDS (17 real f-tiles)
  for (int i=t; i<2176; i+=256){
    int row = i>>3, cin = i&7;
    *(uint4*)&pjs[row*64 + ((cin ^ (row&7))<<3)] = ((const uint4*)pjn)[i];
  }

  const u16* qb = q + ((size_t)(b*SEQ + n0 + w*16 + lr)*DM + hd*64 + lg*8);
  bf16x8 a0 = ldb8(qb), a1 = ldb8(qb+32);
  float sq = 0.f;
  #pragma unroll
  for (int i=0;i<8;i++){ float u0=(float)a0[i], u1=(float)a1[i]; sq += u0*u0 + u1*u1; }
  sq += __shfl_xor(sq,16); sq += __shfl_xor(sq,32);
  float dg = sq*0.0625f;

  __syncthreads();  // pjs ready

  // per-thread swizzled LDS offsets (row = ft*16+lr -> row&7 == lr&7)
  const int sw0 = ((lg ^ (lr&7))<<3);
  const int sw1 = (((lg+4) ^ (lr&7))<<3);

  float mj = -3e38f;
  #pragma unroll
  for (int ft=0; ft<17; ++ft){
    const u16* pb = pjs + (ft*16 + lr)*64;
    f32x4 z = (f32x4){0.f,0.f,0.f,0.f};
    z = MFMA(ldb8(pb + sw0), a0, z);
    z = MFMA(ldb8(pb + sw1), a1, z);
    if (ft < 16){
      #pragma unroll
      for (int j=0;j<4;j++) mj = fmaxf(mj, z[j]);
    } else {
      #pragma unroll
      for (int j=0;j<4;j++) if (lg*4+j < 10) mj = fmaxf(mj, z[j]);
    }
  }
  mj = fmaxf(mj, __shfl_xor(mj,16));
  mj = fmaxf(mj, __shfl_xor(mj,32));

  int s0 = ((lg&1)<<5) + lr;
  int s1 = s0 + 16;
  bool hi = (l >= 32);
  f32x4 oacc[4];
  #pragma unroll
  for (int d=0;d<4;d++) oacc[d]=(f32x4){0.f,0.f,0.f,0.f};
  const u16* cbase = ctxb + (size_t)bh*DH*NFP;
  const float* ksb = ksum + (size_t)bh*NFP;
  float den = 0.f;
  #pragma unroll
  for (int fp=0; fp<9; ++fp){
    int te = 2*fp, to = te+1;
    f32x4 z0 = (f32x4){0.f,0.f,0.f,0.f};
    f32x4 z1 = (f32x4){0.f,0.f,0.f,0.f};
    {
      const u16* pb = pjs + (te*16 + lr)*64;
      z0 = MFMA(ldb8(pb + sw0), a0, z0);
      z0 = MFMA(ldb8(pb + sw1), a1, z0);
    }
    if (to < 17){
      const u16* pb = pjs + (to*16 + lr)*64;
      z1 = MFMA(ldb8(pb + sw0), a0, z1);
      z1 = MFMA(ldb8(pb + sw1), a1, z1);
    }
    f32x4 ks0 = *(const f32x4*)(ksb + te*16 + lg*4);
    f32x4 ks1 = *(const f32x4*)(ksb + to*16 + lg*4);
    int fb0 = te*16 + lg*4, fb1 = to*16 + lg*4;
    float qv0[4], qv1[4];
    #pragma unroll
    for (int j=0;j<4;j++){
      qv0[j] = (fb0 + j < NF) ? RATIO*(__expf(z0[j] - dg - mj) + KEPS) : 0.f;
      den += qv0[j]*ks0[j];
      qv1[j] = (fb1 + j < NF) ? RATIO*(__expf(z1[j] - dg - mj) + KEPS) : 0.f;
      den += qv1[j]*ks1[j];
    }
    unsigned q00 = cvtpk(qv0[0], qv0[1]), q01 = cvtpk(qv0[2], qv0[3]);
    unsigned q10 = cvtpk(qv1[0], qv1[1]), q11 = cvtpk(qv1[2], qv1[3]);
    unsigned e0 = (unsigned)__shfl((int)q00, s0), o0 = (unsigned)__shfl((int)q10, s0);
    unsigned e1 = (unsigned)__shfl((int)q01, s0), o1 = (unsigned)__shfl((int)q11, s0);
    unsigned e2 = (unsigned)__shfl((int)q00, s1), o2 = (unsigned)__shfl((int)q10, s1);
    unsigned e3 = (unsigned)__shfl((int)q01, s1), o3 = (unsigned)__shfl((int)q11, s1);
    union { unsigned u[4]; bf16x8 v; } bw;
    bw.u[0] = hi ? o0 : e0;
    bw.u[1] = hi ? o1 : e1;
    bw.u[2] = hi ? o2 : e2;
    bw.u[3] = hi ? o3 : e3;
    #pragma unroll
    for (int d=0;d<4;d++)
      oacc[d] = MFMA(bw.v, ldb8(&cbase[(d*16 + lr)*NFP + fp*32 + lg*8]), oacc[d]);
  }
  den += __shfl_xor(den,16); den += __shfl_xor(den,32);
  float di = 1.f/den;
  float di4[4];
  #pragma unroll
  for (int j=0;j<4;j++) di4[j] = __shfl(di, lg*4+j);

  u16* obw = ob[w];
  #pragma unroll
  for (int d=0;d<4;d++)
    #pragma unroll
    for (int j=0;j<4;j++)
      obw[(lg*4+j)*72 + d*16 + lr] = f2b(oacc[d][j]*di4[j]);
  asm volatile("s_waitcnt lgkmcnt(0)" ::: "memory");
  {
    int row = l>>3, ck = l&7;
    #pragma unroll
    for (int rr=0; rr<2; ++rr){
      int r2 = row + rr*8;
      uint4 v = *(const uint4*)&obw[r2*72 + ck*8];
      u16* ab = attn + ((size_t)(b*SEQ + n0 + w*16 + r2))*DM + hd*64;
      *(uint4*)(ab + ck*8) = v;
    }
  }
}

// ---------------- max pool (h + ffn bf16 out, f32 add) + head ----------------
__global__ void k_maxpool(const float* __restrict__ h, const u16* __restrict__ fo,
                          float* __restrict__ p){
  int bi = blockIdx.x;
  int b = bi>>5, half = (bi>>4)&1, seg = bi&15;
  int c = half*256 + threadIdx.x;
  size_t base = ((size_t)b*SEQ + seg*128)*DM + c;
  const float* hp = h + base;
  const u16*  fp = fo + base;
  float m = -3e38f;
  for (int n=0;n<128;n++) m = fmaxf(m, hp[(size_t)n*DM] + b2f(fp[(size_t)n*DM]));
  atomicMaxF(&p[b*DM + c], m);
}

__launch_bounds__(256)
__global__ void k_head(const float* __restrict__ p, const float* __restrict__ w1,
                       const float* __restrict__ b1, const float* __restrict__ w2,
                       const float* __restrict__ b2, float* __restrict__ out)
{
  __shared__ float z[DM];
  __shared__ float pr[DM];
  int b = blockIdx.x, t = threadIdx.x;
  pr[t] = p[(size_t)b*DM + t];
  pr[t+256] = p[(size_t)b*DM + t + 256];
  __syncthreads();
  for (int c=t; c<DM; c+=256){
    float a = b1[c];
    for (int k=0;k<DM;k++) a += pr[k]*w1[(size_t)k*DM + c];
    z[c] = fmaxf(a, 0.f);
  }
  __syncthreads();
  if (t < 10){
    float a = b2[t];
    for (int k=0;k<DM;k++) a += z[k]*w2[(size_t)k*10 + t];
    out[b*10 + t] = a;
  }
}

// ---------------- launch ----------------
static inline size_t align256(size_t x){ return (x+255)&~(size_t)255; }

extern "C" void kernel_launch(void* const* d_in, const int* in_sizes, int n_in,
                              void* d_out, int out_size, void* d_ws, size_t ws_size,
                              hipStream_t stream)
{
  (void)in_sizes; (void)n_in; (void)out_size;
  const float* x     = (const float*)d_in[0];
  const float* enc_w = (const float*)d_in[1];
  const float* enc_b = (const float*)d_in[2];
  const float* ln1_g = (const float*)d_in[3];
  const float* ln1_b = (const float*)d_in[4];
  const float* wq    = (const float*)d_in[5];
  const float* bq    = (const float*)d_in[6];
  const float* wk    = (const float*)d_in[7];
  const float* bk    = (const float*)d_in[8];
  const float* wv    = (const float*)d_in[9];
  const float* bv    = (const float*)d_in[10];
  const float* wo    = (const float*)d_in[11];
  const float* bo    = (const float*)d_in[12];
  const float* proj  = (const float*)d_in[13];
  const float* ln2_g = (const float*)d_in[14];
  const float* ln2_b = (const float*)d_in[15];
  const float* ff_w1 = (const float*)d_in[16];
  const float* ff_b1 = (const float*)d_in[17];
  const float* ff_w2 = (const float*)d_in[18];
  const float* ff_b2 = (const float*)d_in[19];
  const float* mw1   = (const float*)d_in[20];
  const float* mb1   = (const float*)d_in[21];
  const float* mw2   = (const float*)d_in[22];
  const float* mb2   = (const float*)d_in[23];

  char* base = (char*)d_ws;
  size_t off = 0;
  auto alloc = [&](size_t bytes)->void*{ void* r = base + off; off = align256(off + bytes); return r; };
  float* h     = (float*)alloc((size_t)ROWS*DM*4);       // 64 MiB residual stream (f32)
  u16*   slotA = (u16*)  alloc((size_t)ROWS*DM*2);       // 32 MiB: y -> attn -> y2 -> ffo
  u16*   wqT   = (u16*)  alloc((size_t)512*512*2);
  u16*   wkvT  = (u16*)  alloc((size_t)1024*512*2);
  u16*   woT   = (u16*)  alloc((size_t)512*512*2);
  u16*   f1T   = (u16*)  alloc((size_t)2048*512*2);
  u16*   f2T   = (u16*)  alloc((size_t)512*2048*2);
  u16*   pjn   = (u16*)  alloc((size_t)NFP*DH*2);
  float* kvb   = (float*)alloc(1024*4);
  float* mk    = (float*)alloc(256);
  float* mkpart= (float*)alloc(1024*4);
  u16*   ctxb  = (u16*)  alloc((size_t)128*DH*NFP*2);
  float* ksum  = (float*)alloc((size_t)128*NFP*4);
  float* pbuf  = (float*)alloc((size_t)NB*DM*4);
  // overlay region: attention-phase buffers vs full-size ffb
  size_t offU = off;
  u16*   slotB = (u16*)  alloc((size_t)ROWS*1024*2);     // 64 MiB: kv -> q
  u16*   ctxp  = (u16*)  alloc((size_t)4*128*DH*NFP*2);  // 18.9 MiB bf16 partials
  float* ksump = (float*)alloc((size_t)4*128*NFP*4);
  size_t off_small = off;
  size_t off_big   = align256(offU + (size_t)ROWS*FFD*2); // 128 MiB ffb
  bool big = (off_big <= ws_size);
  u16* ffb = (u16*)(base + offU);                         // big path: full [ROWS][2048]
  if (off_small > ws_size){
    k_signal<<<1,64,0,stream>>>((float*)d_out, (float)ws_size);
    return;
  }

  u16* y    = slotA;
  u16* attn = slotA;
  u16* ffo  = slotA;   // y dead after FF1 consumes it
  u16* kvB  = slotB;
  u16* qB   = slotB;

  k_prep<<<3180,256,0,stream>>>(wq, wk, wv, wo, ff_w1, ff_w2, proj, bk, bv,
                                wqT, wkvT, woT, f1T, f2T, pjn, kvb, pbuf);

  k_encode_ln<<<ROWS/4,256,0,stream>>>(x, enc_w, enc_b, ln1_g, ln1_b, h, y);
  // KV projection: [ROWS,1024]
  gemm8<1,256><<<(ROWS/256)*(1024/256),512,0,stream>>>(y,512, wkvT,512, kvb, nullptr, kvB, 1024, 512);
  k_kmax<<<1024,256,0,stream>>>(kvB, pjn, mkpart);
  k_kmax_red<<<1,256,0,stream>>>(mkpart, mk);
  k_kpctx<<<512,256,0,stream>>>(kvB, pjn, mk, ctxp, ksump);
  k_reduce<<<9360,256,0,stream>>>(ctxp, ksump, ctxb, ksum);
  // Q projection (kv dead): BN=128 -> 512 blocks, 2/CU
  gemm8<1,128><<<(ROWS/256)*(512/128),512,0,stream>>>(y,512, wqT,512, bq, nullptr, qB, 512, 512);
  k_qp_attn<<<128*32,256,0,stream>>>(qB, pjn, ctxb, ksum, attn);
  gemm8<3,128><<<(ROWS/256)*(512/128),512,0,stream>>>(attn,512, woT,512, bo, h, nullptr, 512, 512);
  k_ln<<<ROWS/4,256,0,stream>>>(h, ln2_g, ln2_b, y);
  if (big){
    gemm8<2,256><<<(ROWS/256)*(2048/256),512,0,stream>>>(y,512, f1T,512, ff_b1, nullptr, ffb, 2048, 512);
    gemm8<1,128><<<(ROWS/256)*(512/128),512,0,stream>>>(ffb,2048, f2T,2048, ff_b2, nullptr, ffo, 512, 2048);
  } else {
    for (int c2=0;c2<2;c2++){
      const u16* ych = y + (size_t)c2*16384*512;
      u16*       fch = ffo + (size_t)c2*16384*512;
      gemm8<2,256><<<(16384/256)*(2048/256),512,0,stream>>>(ych,512, f1T,512, ff_b1, nullptr, ffb, 2048, 512);
      gemm8<1,128><<<(16384/256)*(512/128),512,0,stream>>>(ffb,2048, f2T,2048, ff_b2, nullptr, fch, 512, 2048);
    }
  }
  k_maxpool<<<NB*32,256,0,stream>>>(h, ffo, pbuf);
  k_head<<<NB,256,0,stream>>>(pbuf, mw1, mb1, mw2, mb2, (float*)d_out);
}

// Round 18
// 604.098 us; speedup vs baseline: 1.0266x; 1.0266x over previous
//
#include <hip/hip_runtime.h>
#include <math.h>

typedef unsigned short u16;
typedef __bf16 bf16x8 __attribute__((ext_vector_type(8)));
typedef float f32x4 __attribute__((ext_vector_type(4)));
typedef u16 u16x8 __attribute__((ext_vector_type(8)));

#define DEVI static __device__ __forceinline__

#define NB 16
#define SEQ 2048
#define DM 512
#define DH 64
#define NF 266
#define NFP 288
#define FFD 2048
#define ROWS (NB*SEQ)
#define SQRT_DM 22.62741699796952f
#define DATA_NORM 0.3535533905932738f
#define RATIO 0.0613139073f
#define KEPS 1e-4f

DEVI u16 f2b(float f){
  union{float f; unsigned u;} c; c.f=f;
  unsigned r = c.u + 0x7FFFu + ((c.u>>16)&1u);
  return (u16)(r>>16);
}
DEVI float b2f(u16 v){
  union{unsigned u; float f;} c; c.u = ((unsigned)v)<<16; return c.f;
}
DEVI unsigned cvtpk(float a, float b){
  unsigned r;
  asm("v_cvt_pk_bf16_f32 %0, %1, %2" : "=v"(r) : "v"(a), "v"(b));
  return r;
}

DEVI f32x4 MFMA(bf16x8 a, bf16x8 b, f32x4 c){
  return __builtin_amdgcn_mfma_f32_16x16x32_bf16(a,b,c,0,0,0);
}

DEVI void async16(void* lds, const void* g){
  __builtin_amdgcn_global_load_lds(
      (const __attribute__((address_space(1))) unsigned*)g,
      (__attribute__((address_space(3))) unsigned*)lds, 16, 0, 0);
}

DEVI void atomicMaxF(float* a, float v){
  if (v >= 0.f) atomicMax((int*)a, __float_as_int(v));
  else          atomicMin((unsigned*)a, (unsigned)__float_as_int(v));
}

DEVI bf16x8 ldb8(const u16* p){ return *(const bf16x8*)p; }

// erf via Abramowitz-Stegun 7.1.26 (|err| < 1.5e-7)
DEVI float erf_fast(float u){
  float au = fabsf(u);
  float tt = __builtin_amdgcn_rcpf(1.f + 0.3275911f*au);
  float poly = tt*(0.254829592f + tt*(-0.284496736f + tt*(1.421413741f + tt*(-1.453152027f + tt*1.061405429f))));
  float er = 1.f - poly*__expf(-u*u);
  return copysignf(er, u);
}

// ============ 256xBNT tile GEMM, BK=32, 8 waves, 2-buffer double-buffer ============
// BNT=256: 64KB LDS (2 blocks/CU, grids with N>=1024). BNT=128: 48KB LDS -> N=512 grids
// get 512 blocks = 2 blocks/CU.
// EPI: 1 = bias -> bf16 out; 2 = bias+gelu -> bf16 out; 3 = bias + resid(f32,in-place) -> f32
template<int EPI, int BNT>
__launch_bounds__(512,2)
__global__ void gemm8(const u16* __restrict__ A, int lda,
                      const u16* __restrict__ Bt, int ldb,
                      const float* __restrict__ bias,
                      float* __restrict__ resid,
                      u16* __restrict__ Cb,
                      int N, int K)
{
  constexpr int NREG = BNT/64;            // 4 or 2 accumulator cols per wave
  constexpr int BUFU = 8192 + BNT*32;     // u16 per buffer (A + B)
  __shared__ u16 sm[2*BUFU];
  const int tid = threadIdx.x;
  const int ntn = N / BNT;
  int bid = blockIdx.x;
  const int nwg = gridDim.x;
  if ((nwg & 7) == 0){ int qq = nwg >> 3; bid = (bid & 7)*qq + (bid >> 3); }
  const int bm = bid / ntn, bn = bid % ntn;
  const int wid = tid>>6, l = tid&63, lr = l&15, lg = l>>4;
  const int wm = wid>>2, wn = wid&3;

  // staging source (pre-swizzled chunk)
  const int rA = tid>>2;
  const int cA = (tid&3) ^ ((rA>>1)&3);
  const u16* gA = A  + (size_t)(bm*256 + rA)*lda + cA*8;
  const u16* gB = Bt + (size_t)(bn*BNT + rA)*ldb + cA*8;
  const size_t stepA = (size_t)128*lda, stepB = (size_t)128*ldb;

  // frag read offsets (swizzle constant per thread)
  const int cc = ((lg ^ ((lr>>1)&3))<<3);
  const int aoff = (wm*128 + lr)*32 + cc;
  const int boff = 8192 + (wn*(BNT/4) + lr)*32 + cc;

  const int nt = K >> 5;
  f32x4 acc[8][NREG];
  #pragma unroll
  for (int m=0;m<8;m++)
    #pragma unroll
    for (int n=0;n<NREG;n++) acc[m][n]=(f32x4){0.f,0.f,0.f,0.f};

  // prologue: stage tile 0 into buf0
  {
    u16* sb = &sm[0];
    async16(&sb[tid*8],         gA);
    async16(&sb[4096 + tid*8],  gA + stepA);
    async16(&sb[8192 + tid*8],  gB);
    if (BNT == 256) async16(&sb[12288 + tid*8], gB + stepB);
  }
  asm volatile("s_waitcnt vmcnt(0)" ::: "memory");
  __builtin_amdgcn_s_barrier();
  __builtin_amdgcn_sched_barrier(0);

  for (int t=0; t<nt; ++t){
    if (t+1 < nt){
      u16* sb = &sm[((t+1)&1)*BUFU];
      const u16* a0 = gA + (t+1)*32;
      const u16* b0 = gB + (t+1)*32;
      async16(&sb[tid*8],         a0);
      async16(&sb[4096 + tid*8],  a0 + stepA);
      async16(&sb[8192 + tid*8],  b0);
      if (BNT == 256) async16(&sb[12288 + tid*8], b0 + stepB);
    }
    __builtin_amdgcn_sched_barrier(0);
    const u16* sb = &sm[(t&1)*BUFU];
    bf16x8 af[8], bfr[NREG];
    #pragma unroll
    for (int m=0;m<8;m++) af[m]  = ldb8(&sb[aoff + m*512]);
    #pragma unroll
    for (int n=0;n<NREG;n++) bfr[n] = ldb8(&sb[boff + n*512]);
    __builtin_amdgcn_s_setprio(1);
    #pragma unroll
    for (int m=0;m<8;m++)
      #pragma unroll
      for (int n=0;n<NREG;n++)
        acc[m][n] = MFMA(af[m], bfr[n], acc[m][n]);
    __builtin_amdgcn_s_setprio(0);
    if (t+1 < nt){
      asm volatile("s_waitcnt vmcnt(0)" ::: "memory");
      __builtin_amdgcn_s_barrier();
      __builtin_amdgcn_sched_barrier(0);
    }
  }

  // ---- epilogue ----
  if (EPI == 3){
    const int r0 = bm*256 + wm*128 + lg*4;
    const int c0 = bn*BNT + wn*(BNT/4) + lr;
    #pragma unroll
    for (int m=0;m<8;m++){
      #pragma unroll
      for (int n=0;n<NREG;n++){
        #pragma unroll
        for (int q=0;q<4;q++){
          int r = r0 + m*16 + q;
          int c = c0 + n*16;
          float v = acc[m][n][q] + bias[c];
          size_t idx = (size_t)r*N + c;
          resid[idx] = resid[idx] + v;
        }
      }
    }
  } else {
    // bf16 out: per-wave LDS transpose (staging LDS is dead) -> vectorized 16B stores
    __syncthreads();
    constexpr int OBW = (BNT==256) ? 72 : 40;      // padded row stride (u16)
    constexpr int OWS = (BNT==256) ? 2336 : 1280;  // per-wave region (u16)
    const int c0w = bn*BNT + wn*(BNT/4);
    const int r0m = bm*256 + wm*128;
    #pragma unroll
    for (int m=0;m<8;m++){
      u16* obw = &sm[wid*OWS + (m&1)*(OWS/2)];
      #pragma unroll
      for (int n=0;n<NREG;n++){
        #pragma unroll
        for (int q=0;q<4;q++){
          float v = acc[m][n][q] + bias[c0w + n*16 + lr];
          if (EPI==2) v = 0.5f*v*(1.f + erf_fast(v*0.70710678f));
          obw[(lg*4+q)*OBW + n*16 + lr] = f2b(v);
        }
      }
      asm volatile("s_waitcnt lgkmcnt(0)" ::: "memory");
      if (BNT == 256){
        int rowR = l>>3, ck = l&7;
        #pragma unroll
        for (int rr=0; rr<2; ++rr){
          int r2 = rowR + rr*8;
          uint4 v = *(const uint4*)&obw[r2*OBW + ck*8];
          *(uint4*)(Cb + (size_t)(r0m + m*16 + r2)*N + c0w + ck*8) = v;
        }
      } else {
        int rowR = l>>2, ck = l&3;
        uint4 v = *(const uint4*)&obw[rowR*OBW + ck*8];
        *(uint4*)(Cb + (size_t)(r0m + m*16 + rowR)*N + c0w + ck*8) = v;
      }
    }
  }
}

// ---------------- fused weight prep: LDS-tiled transposes + misc ----------------
__launch_bounds__(256)
__global__ void k_prep(const float* __restrict__ wq, const float* __restrict__ wk,
                       const float* __restrict__ wv, const float* __restrict__ wo,
                       const float* __restrict__ ffw1, const float* __restrict__ ffw2,
                       const float* __restrict__ proj, const float* __restrict__ bk,
                       const float* __restrict__ bv,
                       u16* __restrict__ wqT, u16* __restrict__ wkvT, u16* __restrict__ woT,
                       u16* __restrict__ f1T, u16* __restrict__ f2T, u16* __restrict__ pjn,
                       float* __restrict__ kvb, float* __restrict__ pbuf)
{
  int bid = blockIdx.x, t = threadIdx.x;
  if (bid < 3072){
    const float* src; u16* dst; int R, C, tile;
    if      (bid < 256){ src=wq;  dst=wqT;          R=512; C=512;  tile=bid; }
    else if (bid < 512){ src=wk;  dst=wkvT;         R=512; C=512;  tile=bid-256; }
    else if (bid < 768){ src=wv;  dst=wkvT+262144;  R=512; C=512;  tile=bid-512; }
    else if (bid <1024){ src=wo;  dst=woT;          R=512; C=512;  tile=bid-768; }
    else if (bid <2048){ src=ffw1;dst=f1T;          R=512; C=2048; tile=bid-1024; }
    else               { src=ffw2;dst=f2T;          R=2048;C=512;  tile=bid-2048; }
    int ntc = C>>5;
    int tr = tile/ntc, tc = tile%ntc;
    __shared__ float tl[32][33];
    int r = t>>5, c = t&31;
    #pragma unroll
    for (int it=0; it<4; ++it)
      tl[r+it*8][c] = src[(size_t)(tr*32 + r + it*8)*C + tc*32 + c];
    __syncthreads();
    #pragma unroll
    for (int it=0; it<4; ++it)
      dst[(size_t)(tc*32 + r + it*8)*R + tr*32 + c] = f2b(tl[c][r+it*8]);
    return;
  }
  int i = (bid-3072)*256 + t;
  if (i < NFP*DH){ int f=i>>6, d=i&63; pjn[i] = f2b(f<NF ? proj[(size_t)f*64+d]*DATA_NORM : 0.f); return; }
  i -= NFP*DH;
  if (i < 1024){ kvb[i] = (i<512)? bk[i] : bv[i-512]; return; }
  i -= 1024;
  if (i < NB*DM){ pbuf[i] = -INFINITY; return; }
}

__global__ void k_signal(float* out, float v){
  if (threadIdx.x==0 && blockIdx.x==0) out[0] = v;
}

// ---------------- encoder + LN1 (one wave per row) ----------------
__launch_bounds__(256)
__global__ void k_encode_ln(const float* __restrict__ x, const float* __restrict__ ew,
                            const float* __restrict__ eb, const float* __restrict__ lgw,
                            const float* __restrict__ lbw, float* __restrict__ h,
                            u16* __restrict__ y)
{
  int w = threadIdx.x>>6, l = threadIdx.x&63;
  int row = blockIdx.x*4 + w;
  const float* xr = x + (size_t)row*24;
  float xv[24];
  #pragma unroll
  for (int k=0;k<24;k++) xv[k] = xr[k];
  int c0 = l*8;
  float a[8] = {0,0,0,0,0,0,0,0};
  #pragma unroll
  for (int k=0;k<24;k++){
    const float* wp = ew + (size_t)k*DM + c0;
    #pragma unroll
    for (int c=0;c<8;c++) a[c] += xv[k]*wp[c];
  }
  float s=0.f, s2=0.f;
  #pragma unroll
  for (int c=0;c<8;c++){
    a[c] = (a[c] + eb[c0+c]) * SQRT_DM;
    s += a[c]; s2 += a[c]*a[c];
  }
  #pragma unroll
  for (int m=1;m<64;m<<=1){ s += __shfl_xor(s,m); s2 += __shfl_xor(s2,m); }
  float mu = s*(1.f/DM);
  float rs = rsqrtf(s2*(1.f/DM) - mu*mu + 1e-5f);
  float* hr = h + (size_t)row*DM + c0;
  u16 yv[8];
  #pragma unroll
  for (int c=0;c<8;c++){
    hr[c] = a[c];
    yv[c] = f2b((a[c]-mu)*rs*lgw[c0+c] + lbw[c0+c]);
  }
  *(uint4*)(y + (size_t)row*DM + c0) = *(const uint4*)yv;
}

// ---------------- LN2 ----------------
__launch_bounds__(256)
__global__ void k_ln(const float* __restrict__ h, const float* __restrict__ lgw,
                     const float* __restrict__ lbw, u16* __restrict__ y)
{
  int w = threadIdx.x>>6, l = threadIdx.x&63;
  int row = blockIdx.x*4 + w;
  int c0 = l*8;
  const float* hr = h + (size_t)row*DM + c0;
  float a[8];
  *(float4*)&a[0] = *(const float4*)hr;
  *(float4*)&a[4] = *(const float4*)(hr+4);
  float s=0.f, s2=0.f;
  #pragma unroll
  for (int c=0;c<8;c++){ s += a[c]; s2 += a[c]*a[c]; }
  #pragma unroll
  for (int m=1;m<64;m<<=1){ s += __shfl_xor(s,m); s2 += __shfl_xor(s2,m); }
  float mu = s*(1.f/DM);
  float rs = rsqrtf(s2*(1.f/DM) - mu*mu + 1e-5f);
  u16 yv[8];
  #pragma unroll
  for (int c=0;c<8;c++) yv[c] = f2b((a[c]-mu)*rs*lgw[c0+c] + lbw[c0+c]);
  *(uint4*)(y + (size_t)row*DM + c0) = *(const uint4*)yv;
}

// ---------------- FAVOR+: global max over dd_k ----------------
__launch_bounds__(256,1)
__global__ void k_kmax(const u16* __restrict__ kv, const u16* __restrict__ pjn,
                       float* __restrict__ mkpart)
{
  __shared__ float red[4];
  int t = threadIdx.x, w = t>>6, l = t&63, lr = l&15, lg = l>>4;
  int bh = blockIdx.x>>3, tile = blockIdx.x&7;
  int b = bh>>3, hd = bh&7;
  int row0 = tile*256 + w*64;
  bf16x8 pf0[17], pf1[17];
  #pragma unroll
  for (int f=0; f<17; ++f){
    const u16* pb = pjn + (f*16 + lr)*64 + lg*8;
    pf0[f] = ldb8(pb); pf1[f] = ldb8(pb+32);
  }
  bf16x8 a0[4], a1[4];
  #pragma unroll
  for (int it=0; it<4; ++it){
    const u16* kb = kv + ((size_t)(b*SEQ + row0 + it*16 + lr)*1024 + hd*64 + lg*8);
    a0[it] = ldb8(kb); a1[it] = ldb8(kb+32);
  }
  float vmax = -3e38f;
  #pragma unroll
  for (int it=0; it<4; ++it){
    #pragma unroll
    for (int f=0; f<17; ++f){
      f32x4 z = (f32x4){0.f,0.f,0.f,0.f};
      z = MFMA(a0[it], pf0[f], z);
      z = MFMA(a1[it], pf1[f], z);
      if (f*16 + lr < NF){
        #pragma unroll
        for (int j=0;j<4;j++) vmax = fmaxf(vmax, z[j]);
      }
    }
  }
  #pragma unroll
  for (int m=1;m<64;m<<=1) vmax = fmaxf(vmax, __shfl_xor(vmax,m));
  if (l==0) red[w] = vmax;
  __syncthreads();
  if (t==0) mkpart[blockIdx.x] = fmaxf(fmaxf(red[0],red[1]), fmaxf(red[2],red[3]));
}

__global__ void k_kmax_red(const float* __restrict__ mkpart, float* __restrict__ mk){
  __shared__ float red[4];
  int t = threadIdx.x, w = t>>6, l = t&63;
  float v = fmaxf(fmaxf(mkpart[t], mkpart[t+256]), fmaxf(mkpart[t+512], mkpart[t+768]));
  #pragma unroll
  for (int m=1;m<64;m<<=1) v = fmaxf(v, __shfl_xor(v,m));
  if (l==0) red[w] = v;
  __syncthreads();
  if (t==0) mk[0] = fmaxf(fmaxf(red[0],red[1]), fmaxf(red[2],red[3]));
}

// ---------------- FAVOR+: kp -> ctx^T partials (bf16) + ksum partials ----------------
__launch_bounds__(256,2)
__global__ void k_kpctx(const u16* __restrict__ kv, const u16* __restrict__ pjn,
                        const float* __restrict__ mkp,
                        u16* __restrict__ ctxp, float* __restrict__ ksump)
{
  __shared__ u16 pjs[272*64];    // [272 f][64 d], 16B chunks XOR-swizzled by (row&7)
  __shared__ u16 vT[DH*32];      // [64 d][32 n], 16B chunks XOR-swizzled by (row>>1)&3
  __shared__ u16 kpT[NFP*32];    // [288 f][32 n], same swizzle
  __shared__ float dbuf[4][16];
  int t = threadIdx.x, w = t>>6, l = t&63, lr = l&15, lg = l>>4;
  int bh = blockIdx.x>>2, seg = blockIdx.x&3;
  int b = bh>>3, hd = bh&7;
  int mw = w>>1, fh = (w&1)*9;
  float mk = *mkp;

  // stage proj (first 17 f-tiles; tile 17 is all zeros -> handled in code)
  for (int i=t; i<2176; i+=256){
    int row = i>>3, cin = i&7;
    *(uint4*)&pjs[row*64 + ((cin ^ (row&7))<<3)] = ((const uint4*)pjn)[i];
  }

  f32x4 ctxa[18];
  #pragma unroll
  for (int f=0;f<18;f++) ctxa[f]=(f32x4){0.f,0.f,0.f,0.f};
  float ksa[9];
  #pragma unroll
  for (int i=0;i<9;i++) ksa[i]=0.f;

  for (int ch=0; ch<16; ++ch){
    int n0 = seg*512 + ch*32;
    __syncthreads();
    {  // stage v^T (swizzled chunks)
      int nl = t>>3, d0 = (t&7)*8;
      const u16* vsrc = kv + ((size_t)(b*SEQ + n0 + nl)*1024 + 512 + hd*64 + d0);
      uint4 vv = *(const uint4*)vsrc;
      const u16* vp = (const u16*)&vv;
      #pragma unroll
      for (int i=0;i<8;i++){
        int row = d0+i;
        vT[row*32 + (((nl>>3) ^ ((row>>1)&3))<<3) + (nl&7)] = vp[i];
      }
    }
    const u16* kb = kv + ((size_t)(b*SEQ + n0 + mw*16 + lr)*1024 + hd*64 + lg*8);
    bf16x8 a0 = ldb8(kb), a1 = ldb8(kb+32);
    float sq = 0.f;
    #pragma unroll
    for (int i=0;i<8;i++){ float u0=(float)a0[i], u1=(float)a1[i]; sq += u0*u0 + u1*u1; }
    sq += __shfl_xor(sq,16); sq += __shfl_xor(sq,32);
    if (l<16) dbuf[w][l] = sq*0.0625f;
    #pragma unroll
    for (int ff=0; ff<9; ++ff){
      int f = fh + ff;
      f32x4 z = (f32x4){0.f,0.f,0.f,0.f};
      if (f < 17){
        int row = f*16 + lr;
        const u16* pb0 = pjs + row*64 + ((lg ^ (lr&7))<<3);
        const u16* pb1 = pjs + row*64 + (((lg+4) ^ (lr&7))<<3);
        z = MFMA(a0, ldb8(pb0), z);
        z = MFMA(a1, ldb8(pb1), z);
      }
      float kp0 = RATIO*(__expf(z[0] - dbuf[w][lg*4+0] - mk) + KEPS);
      float kp1 = RATIO*(__expf(z[1] - dbuf[w][lg*4+1] - mk) + KEPS);
      float kp2 = RATIO*(__expf(z[2] - dbuf[w][lg*4+2] - mk) + KEPS);
      float kp3 = RATIO*(__expf(z[3] - dbuf[w][lg*4+3] - mk) + KEPS);
      ksa[ff] += kp0 + kp1 + kp2 + kp3;
      ushort4 kw;
      kw.x = f2b(kp0); kw.y = f2b(kp1); kw.z = f2b(kp2); kw.w = f2b(kp3);
      int row = f*16 + lr;
      int wch = (mw*2 + (lg>>1)) ^ ((row>>1)&3);
      *(ushort4*)&kpT[row*32 + (wch<<3) + ((lg&1)<<2)] = kw;
    }
    __syncthreads();
    int rr = w*16 + lr;
    bf16x8 av = ldb8(&vT[rr*32 + ((lg ^ ((rr>>1)&3))<<3)]);
    #pragma unroll
    for (int f=0;f<18;f++){
      int row = f*16 + lr;
      ctxa[f] = MFMA(av, ldb8(&kpT[row*32 + ((lg ^ ((row>>1)&3))<<3)]), ctxa[f]);
    }
  }

  // ---- transposed, vectorized ctx^T partial store ----
  __syncthreads();  // main loop done; pjs/kpT reusable as f32 [16][288] transpose buffers
  {
    float* tb = (w&1) ? (float*)pjs : (float*)kpT;
    u16* dstq = ctxp + (((size_t)seg*128 + bh)*DH + w*16)*NFP;
    #pragma unroll
    for (int r=0; r<2; ++r){
      if ((w>>1) == r){
        #pragma unroll
        for (int f=0;f<18;f++)
          #pragma unroll
          for (int j=0;j<4;j++)
            tb[(lg*4+j)*NFP + f*16 + lr] = ctxa[f][j];
        asm volatile("s_waitcnt lgkmcnt(0)" ::: "memory");
        #pragma unroll
        for (int k=0;k<9;k++){
          int c = k*64 + l;
          f32x4 v0 = *(const f32x4*)(tb + c*8);
          f32x4 v1 = *(const f32x4*)(tb + c*8 + 4);
          u16x8 o;
          o[0]=f2b(v0[0]); o[1]=f2b(v0[1]); o[2]=f2b(v0[2]); o[3]=f2b(v0[3]);
          o[4]=f2b(v1[0]); o[5]=f2b(v1[1]); o[6]=f2b(v1[2]); o[7]=f2b(v1[3]);
          *(u16x8*)(dstq + c*8) = o;
        }
      }
      __syncthreads();
    }
  }
  // ksum partial store: [seg][bh][288]
  #pragma unroll
  for (int ff=0;ff<9;ff++){
    float v = ksa[ff];
    v += __shfl_xor(v,16); v += __shfl_xor(v,32);
    if (l<16) ksump[((size_t)seg*128 + bh)*NFP + (fh+ff)*16 + l] = v;
  }
}

// ---------------- reduce 4 ctx partials (bf16) + 4 ksum partials ----------------
__global__ void k_reduce(const u16* __restrict__ ctxp, const float* __restrict__ ksump,
                         u16* __restrict__ ctxb, float* __restrict__ ksum)
{
  const size_t CT = (size_t)128*DH*NFP;
  const size_t KT = (size_t)128*NFP;
  size_t i = (size_t)blockIdx.x*256 + threadIdx.x;
  if (i < CT){
    float s = b2f(ctxp[i]) + b2f(ctxp[i+CT]) + b2f(ctxp[i+2*CT]) + b2f(ctxp[i+3*CT]);
    ctxb[i] = f2b(s);
  } else if (i < CT + KT){
    size_t j = i - CT;
    ksum[j] = ksump[j] + ksump[j+KT] + ksump[j+2*KT] + ksump[j+3*KT];
  }
}

// ---------------- FAVOR+: qp + attention out ((256,3), 84 VGPR; pjn staged in LDS) ----------------
__launch_bounds__(256,3)
__global__ void k_qp_attn(const u16* __restrict__ q, const u16* __restrict__ pjn,
                          const u16* __restrict__ ctxb, const float* __restrict__ ksum,
                          u16* __restrict__ attn)
{
  __shared__ u16 pjs[272*64];    // 34.8 KB, same (row&7) XOR-swizzle as k_kpctx
  __shared__ u16 ob[4][16*72];
  int t = threadIdx.x, w = t>>6, l = t&63, lr = l&15, lg = l>>4;
  int bh = blockIdx.x>>5, tile = blockIdx.x&31;
  int b = bh>>3, hd = bh&7;
  int n0 = tile*64;

  // stage proj into LDS (17 real f-tiles)
  for (int i=t; i<2176; i+=256){
    int row = i>>3, cin = i&7;
    *(uint4*)&pjs[row*64 + ((cin ^ (row&7))<<3)] = ((const uint4*)pjn)[i];
  }

  const u16* qb = q + ((size_t)(b*SEQ + n0 + w*16 + lr)*DM + hd*64 + lg*8);
  bf16x8 a0 = ldb8(qb), a1 = ldb8(qb+32);
  float sq = 0.f;
  #pragma unroll
  for (int i=0;i<8;i++){ float u0=(float)a0[i], u1=(float)a1[i]; sq += u0*u0 + u1*u1; }
  sq += __shfl_xor(sq,16); sq += __shfl_xor(sq,32);
  float dg = sq*0.0625f;

  __syncthreads();  // pjs ready

  // per-thread swizzled LDS offsets (row = ft*16+lr -> row&7 == lr&7)
  const int sw0 = ((lg ^ (lr&7))<<3);
  const int sw1 = (((lg+4) ^ (lr&7))<<3);

  float mj = -3e38f;
  #pragma unroll
  for (int ft=0; ft<17; ++ft){
    const u16* pb = pjs + (ft*16 + lr)*64;
    f32x4 z = (f32x4){0.f,0.f,0.f,0.f};
    z = MFMA(ldb8(pb + sw0), a0, z);
    z = MFMA(ldb8(pb + sw1), a1, z);
    if (ft < 16){
      #pragma unroll
      for (int j=0;j<4;j++) mj = fmaxf(mj, z[j]);
    } else {
      #pragma unroll
      for (int j=0;j<4;j++) if (lg*4+j < 10) mj = fmaxf(mj, z[j]);
    }
  }
  mj = fmaxf(mj, __shfl_xor(mj,16));
  mj = fmaxf(mj, __shfl_xor(mj,32));

  int s0 = ((lg&1)<<5) + lr;
  int s1 = s0 + 16;
  bool hi = (l >= 32);
  f32x4 oacc[4];
  #pragma unroll
  for (int d=0;d<4;d++) oacc[d]=(f32x4){0.f,0.f,0.f,0.f};
  const u16* cbase = ctxb + (size_t)bh*DH*NFP;
  const float* ksb = ksum + (size_t)bh*NFP;
  float den = 0.f;
  #pragma unroll
  for (int fp=0; fp<9; ++fp){
    int te = 2*fp, to = te+1;
    f32x4 z0 = (f32x4){0.f,0.f,0.f,0.f};
    f32x4 z1 = (f32x4){0.f,0.f,0.f,0.f};
    {
      const u16* pb = pjs + (te*16 + lr)*64;
      z0 = MFMA(ldb8(pb + sw0), a0, z0);
      z0 = MFMA(ldb8(pb + sw1), a1, z0);
    }
    if (to < 17){
      const u16* pb = pjs + (to*16 + lr)*64;
      z1 = MFMA(ldb8(pb + sw0), a0, z1);
      z1 = MFMA(ldb8(pb + sw1), a1, z1);
    }
    f32x4 ks0 = *(const f32x4*)(ksb + te*16 + lg*4);
    f32x4 ks1 = *(const f32x4*)(ksb + to*16 + lg*4);
    int fb0 = te*16 + lg*4, fb1 = to*16 + lg*4;
    float qv0[4], qv1[4];
    #pragma unroll
    for (int j=0;j<4;j++){
      qv0[j] = (fb0 + j < NF) ? RATIO*(__expf(z0[j] - dg - mj) + KEPS) : 0.f;
      den += qv0[j]*ks0[j];
      qv1[j] = (fb1 + j < NF) ? RATIO*(__expf(z1[j] - dg - mj) + KEPS) : 0.f;
      den += qv1[j]*ks1[j];
    }
    unsigned q00 = cvtpk(qv0[0], qv0[1]), q01 = cvtpk(qv0[2], qv0[3]);
    unsigned q10 = cvtpk(qv1[0], qv1[1]), q11 = cvtpk(qv1[2], qv1[3]);
    unsigned e0 = (unsigned)__shfl((int)q00, s0), o0 = (unsigned)__shfl((int)q10, s0);
    unsigned e1 = (unsigned)__shfl((int)q01, s0), o1 = (unsigned)__shfl((int)q11, s0);
    unsigned e2 = (unsigned)__shfl((int)q00, s1), o2 = (unsigned)__shfl((int)q10, s1);
    unsigned e3 = (unsigned)__shfl((int)q01, s1), o3 = (unsigned)__shfl((int)q11, s1);
    union { unsigned u[4]; bf16x8 v; } bw;
    bw.u[0] = hi ? o0 : e0;
    bw.u[1] = hi ? o1 : e1;
    bw.u[2] = hi ? o2 : e2;
    bw.u[3] = hi ? o3 : e3;
    #pragma unroll
    for (int d=0;d<4;d++)
      oacc[d] = MFMA(bw.v, ldb8(&cbase[(d*16 + lr)*NFP + fp*32 + lg*8]), oacc[d]);
  }
  den += __shfl_xor(den,16); den += __shfl_xor(den,32);
  float di = 1.f/den;
  float di4[4];
  #pragma unroll
  for (int j=0;j<4;j++) di4[j] = __shfl(di, lg*4+j);

  u16* obw = ob[w];
  #pragma unroll
  for (int d=0;d<4;d++)
    #pragma unroll
    for (int j=0;j<4;j++)
      obw[(lg*4+j)*72 + d*16 + lr] = f2b(oacc[d][j]*di4[j]);
  asm volatile("s_waitcnt lgkmcnt(0)" ::: "memory");
  {
    int row = l>>3, ck = l&7;
    #pragma unroll
    for (int rr=0; rr<2; ++rr){
      int r2 = row + rr*8;
      uint4 v = *(const uint4*)&obw[r2*72 + ck*8];
      u16* ab = attn + ((size_t)(b*SEQ + n0 + w*16 + r2))*DM + hd*64;
      *(uint4*)(ab + ck*8) = v;
    }
  }
}

// ---------------- max pool (h + ffn bf16 out, f32 add) + head ----------------
__global__ void k_maxpool(const float* __restrict__ h, const u16* __restrict__ fo,
                          float* __restrict__ p){
  int bi = blockIdx.x;
  int b = bi>>5, half = (bi>>4)&1, seg = bi&15;
  int c = half*256 + threadIdx.x;
  size_t base = ((size_t)b*SEQ + seg*128)*DM + c;
  const float* hp = h + base;
  const u16*  fp = fo + base;
  float m = -3e38f;
  for (int n=0;n<128;n++) m = fmaxf(m, hp[(size_t)n*DM] + b2f(fp[(size_t)n*DM]));
  atomicMaxF(&p[b*DM + c], m);
}

__launch_bounds__(256)
__global__ void k_head(const float* __restrict__ p, const float* __restrict__ w1,
                       const float* __restrict__ b1, const float* __restrict__ w2,
                       const float* __restrict__ b2, float* __restrict__ out)
{
  __shared__ float z[DM];
  __shared__ float pr[DM];
  int b = blockIdx.x, t = threadIdx.x;
  pr[t] = p[(size_t)b*DM + t];
  pr[t+256] = p[(size_t)b*DM + t + 256];
  __syncthreads();
  for (int c=t; c<DM; c+=256){
    float a = b1[c];
    for (int k=0;k<DM;k++) a += pr[k]*w1[(size_t)k*DM + c];
    z[c] = fmaxf(a, 0.f);
  }
  __syncthreads();
  if (t < 10){
    float a = b2[t];
    for (int k=0;k<DM;k++) a += z[k]*w2[(size_t)k*10 + t];
    out[b*10 + t] = a;
  }
}

// ---------------- launch ----------------
static inline size_t align256(size_t x){ return (x+255)&~(size_t)255; }

extern "C" void kernel_launch(void* const* d_in, const int* in_sizes, int n_in,
                              void* d_out, int out_size, void* d_ws, size_t ws_size,
                              hipStream_t stream)
{
  (void)in_sizes; (void)n_in; (void)out_size;
  const float* x     = (const float*)d_in[0];
  const float* enc_w = (const float*)d_in[1];
  const float* enc_b = (const float*)d_in[2];
  const float* ln1_g = (const float*)d_in[3];
  const float* ln1_b = (const float*)d_in[4];
  const float* wq    = (const float*)d_in[5];
  const float* bq    = (const float*)d_in[6];
  const float* wk    = (const float*)d_in[7];
  const float* bk    = (const float*)d_in[8];
  const float* wv    = (const float*)d_in[9];
  const float* bv    = (const float*)d_in[10];
  const float* wo    = (const float*)d_in[11];
  const float* bo    = (const float*)d_in[12];
  const float* proj  = (const float*)d_in[13];
  const float* ln2_g = (const float*)d_in[14];
  const float* ln2_b = (const float*)d_in[15];
  const float* ff_w1 = (const float*)d_in[16];
  const float* ff_b1 = (const float*)d_in[17];
  const float* ff_w2 = (const float*)d_in[18];
  const float* ff_b2 = (const float*)d_in[19];
  const float* mw1   = (const float*)d_in[20];
  const float* mb1   = (const float*)d_in[21];
  const float* mw2   = (const float*)d_in[22];
  const float* mb2   = (const float*)d_in[23];

  char* base = (char*)d_ws;
  size_t off = 0;
  auto alloc = [&](size_t bytes)->void*{ void* r = base + off; off = align256(off + bytes); return r; };
  float* h     = (float*)alloc((size_t)ROWS*DM*4);       // 64 MiB residual stream (f32)
  u16*   slotA = (u16*)  alloc((size_t)ROWS*DM*2);       // 32 MiB: y -> attn -> y2 -> ffo
  u16*   wqT   = (u16*)  alloc((size_t)512*512*2);
  u16*   wkvT  = (u16*)  alloc((size_t)1024*512*2);
  u16*   woT   = (u16*)  alloc((size_t)512*512*2);
  u16*   f1T   = (u16*)  alloc((size_t)2048*512*2);
  u16*   f2T   = (u16*)  alloc((size_t)512*2048*2);
  u16*   pjn   = (u16*)  alloc((size_t)NFP*DH*2);
  float* kvb   = (float*)alloc(1024*4);
  float* mk    = (float*)alloc(256);
  float* mkpart= (float*)alloc(1024*4);
  u16*   ctxb  = (u16*)  alloc((size_t)128*DH*NFP*2);
  float* ksum  = (float*)alloc((size_t)128*NFP*4);
  float* pbuf  = (float*)alloc((size_t)NB*DM*4);
  // overlay region: attention-phase buffers vs full-size ffb
  size_t offU = off;
  u16*   slotB = (u16*)  alloc((size_t)ROWS*1024*2);     // 64 MiB: kv -> q
  u16*   ctxp  = (u16*)  alloc((size_t)4*128*DH*NFP*2);  // 18.9 MiB bf16 partials
  float* ksump = (float*)alloc((size_t)4*128*NFP*4);
  size_t off_small = off;
  size_t off_big   = align256(offU + (size_t)ROWS*FFD*2); // 128 MiB ffb
  bool big = (off_big <= ws_size);
  u16* ffb = (u16*)(base + offU);                         // big path: full [ROWS][2048]
  if (off_small > ws_size){
    k_signal<<<1,64,0,stream>>>((float*)d_out, (float)ws_size);
    return;
  }

  u16* y    = slotA;
  u16* attn = slotA;
  u16* ffo  = slotA;   // y dead after FF1 consumes it
  u16* kvB  = slotB;
  u16* qB   = slotB;

  k_prep<<<3180,256,0,stream>>>(wq, wk, wv, wo, ff_w1, ff_w2, proj, bk, bv,
                                wqT, wkvT, woT, f1T, f2T, pjn, kvb, pbuf);

  k_encode_ln<<<ROWS/4,256,0,stream>>>(x, enc_w, enc_b, ln1_g, ln1_b, h, y);
  // KV projection: [ROWS,1024] (512 blocks, 2/CU)
  gemm8<1,256><<<(ROWS/256)*(1024/256),512,0,stream>>>(y,512, wkvT,512, kvb, nullptr, kvB, 1024, 512);
  k_kmax<<<1024,256,0,stream>>>(kvB, pjn, mkpart);
  k_kmax_red<<<1,256,0,stream>>>(mkpart, mk);
  k_kpctx<<<512,256,0,stream>>>(kvB, pjn, mk, ctxp, ksump);
  k_reduce<<<9360,256,0,stream>>>(ctxp, ksump, ctxb, ksum);
  // Q projection (kv dead): BN=128 -> 512 blocks, 2/CU
  gemm8<1,128><<<(ROWS/256)*(512/128),512,0,stream>>>(y,512, wqT,512, bq, nullptr, qB, 512, 512);
  k_qp_attn<<<128*32,256,0,stream>>>(qB, pjn, ctxb, ksum, attn);
  gemm8<3,128><<<(ROWS/256)*(512/128),512,0,stream>>>(attn,512, woT,512, bo, h, nullptr, 512, 512);
  k_ln<<<ROWS/4,256,0,stream>>>(h, ln2_g, ln2_b, y);
  if (big){
    gemm8<2,256><<<(ROWS/256)*(2048/256),512,0,stream>>>(y,512, f1T,512, ff_b1, nullptr, ffb, 2048, 512);
    gemm8<1,128><<<(ROWS/256)*(512/128),512,0,stream>>>(ffb,2048, f2T,2048, ff_b2, nullptr, ffo, 512, 2048);
  } else {
    for (int c2=0;c2<2;c2++){
      const u16* ych = y + (size_t)c2*16384*512;
      u16*       fch = ffo + (size_t)c2*16384*512;
      gemm8<2,256><<<(16384/256)*(2048/256),512,0,stream>>>(ych,512, f1T,512, ff_b1, nullptr, ffb, 2048, 512);
      gemm8<1,128><<<(16384/256)*(512/128),512,0,stream>>>(ffb,2048, f2T,2048, ff_b2, nullptr, fch, 512, 2048);
    }
  }
  k_maxpool<<<NB*32,256,0,stream>>>(h, ffo, pbuf);
  k_head<<<NB,256,0,stream>>>(pbuf, mw1, mb1, mw2, mb2, (float*)d_out);
}